// Round 7
// baseline (364.986 us; speedup 1.0000x reference)
//
#include <hip/hip_runtime.h>
#include <hip/hip_bf16.h>
#include <hip/hip_fp16.h>

// ---------------------------------------------------------------------------
// 2-layer GAT (PyG GATConv semantics).
// Round 18 = round 17 + ONE delta: aggregate gathers moved from L3 to L2.
//   h16 becomes head-major [4][N][64] (gemm epilogue writes the head slice);
//   aggregate blocks are head-partitioned (hd = bid&3, grid 20000 = N/4*4,
//   %8==0) so each block touches only its 2.56MB head slice -> L2-resident
//   on its XCD. Wave = one node-head; lane = (edge-half, channel-pair):
//   per 8-edge iter, 8 uniform scalar idx+score loads, 4x 32-lane 128B-
//   contiguous gathers, r14's clamp+ex=0 branchless tail. Epilogue = one
//   shfl_xor(32) for den/acc. 338MB/dispatch of h16 gather traffic now
//   served by L2 (~34.5 TB/s) instead of L3.
// Everything else byte-for-byte r17: XCD-bucketed ell_scatter; LDS-staged
// split-bf16 MFMA GEMM with fused attention-score epilogue; padded per-line
// counters zeroed inside pack_w12; fused mean+bias+Wout output head.
// ---------------------------------------------------------------------------

#define HEADS 4
#define CDIM 64
#define HC 256   // HEADS*CDIM
#define ELLW 96  // ELL row stride (ints)
#define CNTS 16  // cnt stride in ints (64B line per counter)
#define NCHUNK 320  // edge chunks; grid = NCHUNK*8 (nwg%8==0)

typedef __attribute__((ext_vector_type(8))) short bf16x8;   // 8 bf16 = 4 VGPR
typedef __attribute__((ext_vector_type(4))) float f32x4;    // MFMA acc

__device__ __forceinline__ short f32_to_bf16_rne(float v) {
  unsigned u = __float_as_uint(v);
  unsigned r = (u + 0x7FFFu + ((u >> 16) & 1u)) >> 16;
  return (short)r;
}
__device__ __forceinline__ float bf16_bits_to_f32(short s) {
  return __uint_as_float(((unsigned)(unsigned short)s) << 16);
}

// acc_lo += f16lo(reg)*ex ; acc_hi += f16hi(reg)*ex   (f32 accumulate)
__device__ __forceinline__ void fma_mix2(float& alo, float& ahi,
                                         unsigned reg, float ex) {
  asm("v_fma_mix_f32 %0, %2, %3, %0 op_sel:[0,0,0] op_sel_hi:[1,0,0]\n\t"
      "v_fma_mix_f32 %1, %2, %3, %1 op_sel:[1,0,0] op_sel_hi:[1,0,0]"
      : "+v"(alo), "+v"(ahi)
      : "v"(reg), "v"(ex));
}

// ------ weight pack (W1+W2 one launch) + cnt-line zeroing (fused) ----------
__global__ __launch_bounds__(256) void pack_w12_kernel(
    const float* __restrict__ W1, short* __restrict__ W1h,
    short* __restrict__ W1l, const float* __restrict__ W2,
    short* __restrict__ W2h, short* __restrict__ W2l,
    int* __restrict__ cnt, int N) {
  const int i = blockIdx.x * 256 + threadIdx.x;
  if (i < N) cnt[i * CNTS] = 0;   // one counter per 64B line
  if (i < 128 * 256) {
    const int k = i >> 8, n = i & 255;
    const float v = W1[i];
    const short hi = f32_to_bf16_rne(v);
    W1h[n * 128 + k] = hi;
    W1l[n * 128 + k] = f32_to_bf16_rne(v - bf16_bits_to_f32(hi));
  } else {
    const int j = i - 128 * 256;
    if (j >= 256 * 256) return;
    const int k = j >> 8, n = j & 255;
    const float v = W2[j];
    const short hi = f32_to_bf16_rne(v);
    W2h[n * 256 + k] = hi;
    W2l[n * 256 + k] = f32_to_bf16_rne(v - bf16_bits_to_f32(hi));
  }
}

// ---------------- split-bf16 MFMA GEMM: h = A[M,K] @ W[K,256] --------------
// block = 128 thr (2 waves); wave w: cols col0 = by*128 + w*64 (one head).
// A staged f32->hi/lo bf16 through LDS; B frags direct from global
// (L2-resident). Epilogue: f16 h write (HEAD-MAJOR [4][M][64]) + fused
// a_s/a_d scores.
__global__ __launch_bounds__(128) void gemm_mfma_split(
    const float* __restrict__ A, const short* __restrict__ Wt_hi,
    const short* __restrict__ Wt_lo, __half* __restrict__ h16,
    const float* __restrict__ att_s, const float* __restrict__ att_d,
    float* __restrict__ a_s, float* __restrict__ a_d, int M, int K) {
  __shared__ alignas(16) short As_hi[64 * 32];
  __shared__ alignas(16) short As_lo[64 * 32];
  const int t = threadIdx.x;
  const int wave = t >> 6;
  const int lane = t & 63;
  const int quad = lane >> 4;
  const int m16 = lane & 15;
  const int row0 = blockIdx.x * 64;
  const int col0 = blockIdx.y * 128 + wave * 64;   // == head*64
  const int head = col0 >> 6;

  f32x4 acc[4][4] = {};  // [mt][nt]

  for (int k0 = 0; k0 < K; k0 += 32) {
    if (k0) __syncthreads();
#pragma unroll
    for (int uu = 0; uu < 2; ++uu) {
      const int u = t + uu * 128;       // 0..255
      const int r = u >> 2, seg = u & 3;
      const int gr = row0 + r;
      float vv[8] = {0.f, 0.f, 0.f, 0.f, 0.f, 0.f, 0.f, 0.f};
      if (gr < M) {
        const float* ap = A + (size_t)gr * K + k0 + seg * 8;
        const float4 v0 = *(const float4*)ap;
        const float4 v1 = *(const float4*)(ap + 4);
        vv[0] = v0.x; vv[1] = v0.y; vv[2] = v0.z; vv[3] = v0.w;
        vv[4] = v1.x; vv[5] = v1.y; vv[6] = v1.z; vv[7] = v1.w;
      }
      bf16x8 h8, l8;
#pragma unroll
      for (int j = 0; j < 8; ++j) {
        const short hi = f32_to_bf16_rne(vv[j]);
        h8[j] = hi;
        l8[j] = f32_to_bf16_rne(vv[j] - bf16_bits_to_f32(hi));
      }
      *(bf16x8*)(As_hi + r * 32 + seg * 8) = h8;
      *(bf16x8*)(As_lo + r * 32 + seg * 8) = l8;
    }
    bf16x8 b_hi[4], b_lo[4];
#pragma unroll
    for (int nt = 0; nt < 4; ++nt) {
      const size_t off = (size_t)(col0 + nt * 16 + m16) * K + k0 + quad * 8;
      b_hi[nt] = *(const bf16x8*)(Wt_hi + off);
      b_lo[nt] = *(const bf16x8*)(Wt_lo + off);
    }
    __syncthreads();
    bf16x8 a_hi[4], a_lo[4];
#pragma unroll
    for (int mt = 0; mt < 4; ++mt) {
      const int off = (mt * 16 + m16) * 32 + quad * 8;
      a_hi[mt] = *(const bf16x8*)(As_hi + off);
      a_lo[mt] = *(const bf16x8*)(As_lo + off);
    }
#pragma unroll
    for (int mt = 0; mt < 4; ++mt)
#pragma unroll
      for (int nt = 0; nt < 4; ++nt) {
        acc[mt][nt] = __builtin_amdgcn_mfma_f32_16x16x32_bf16(
            a_hi[mt], b_hi[nt], acc[mt][nt], 0, 0, 0);
        acc[mt][nt] = __builtin_amdgcn_mfma_f32_16x16x32_bf16(
            a_hi[mt], b_lo[nt], acc[mt][nt], 0, 0, 0);
        acc[mt][nt] = __builtin_amdgcn_mfma_f32_16x16x32_bf16(
            a_lo[mt], b_hi[nt], acc[mt][nt], 0, 0, 0);
      }
  }
  float sa[4], da[4];
#pragma unroll
  for (int nt = 0; nt < 4; ++nt) {
    sa[nt] = att_s[col0 + nt * 16 + m16];
    da[nt] = att_d[col0 + nt * 16 + m16];
  }
  __half* __restrict__ hsl = h16 + (size_t)head * M * CDIM;  // head slice
#pragma unroll
  for (int mt = 0; mt < 4; ++mt)
#pragma unroll
    for (int r = 0; r < 4; ++r) {
      const int gr = row0 + mt * 16 + quad * 4 + r;
      float ps = acc[mt][0][r] * sa[0] + acc[mt][1][r] * sa[1] +
                 acc[mt][2][r] * sa[2] + acc[mt][3][r] * sa[3];
      float pd = acc[mt][0][r] * da[0] + acc[mt][1][r] * da[1] +
                 acc[mt][2][r] * da[2] + acc[mt][3][r] * da[3];
#pragma unroll
      for (int off = 1; off <= 8; off <<= 1) {
        ps += __shfl_xor(ps, off);
        pd += __shfl_xor(pd, off);
      }
      if (gr < M) {
        if (m16 == 0) {
          a_s[gr * HEADS + head] = ps;
          a_d[gr * HEADS + head] = pd;
        }
#pragma unroll
        for (int nt = 0; nt < 4; ++nt)
          hsl[(size_t)gr * CDIM + nt * 16 + m16] =
              __float2half(acc[mt][nt][r]);
      }
    }
}

// ============ ELL build: XCD-bucketed scatter (write-combining) ============
// grid = NCHUNK*8. block (chunk = bx>>3, g = bx&7) scans its chunk's edges
// and keeps those with dst-bucket group ((d>>8)&7) == g.
__global__ __launch_bounds__(256) void ell_scatter_kernel(
    const int* __restrict__ src, const int* __restrict__ dst,
    int* __restrict__ cnt, int* __restrict__ ell, int E_raw, int Etot,
    int chunk_sz) {
  const int g = blockIdx.x & 7;
  const int e0 = (blockIdx.x >> 3) * chunk_sz;
  int e1 = e0 + chunk_sz;
  if (e1 > Etot) e1 = Etot;
  for (int e = e0 + threadIdx.x; e < e1; e += 256) {
    const int d = (e < E_raw) ? dst[e] : (e - E_raw);
    if (((d >> 8) & 7) != g) continue;
    const int s = (e < E_raw) ? src[e] : (e - E_raw);
    const int pos = atomicAdd(&cnt[d * CNTS], 1);
    if (pos < ELLW) ell[d * ELLW + pos] = s;  // P(overflow) ~ 7e-18
  }
}

// ================= fused softmax + aggregation (f16 gather) ================
// r18: head-partitioned, L2-resident. grid = (N/4)*4 blocks x 256 thr.
// block: head hd = bid&3 (XCD-affine via %8 round-robin: bid&7 in {hd,hd+4}),
// nodes 4*(bid>>2)..+3 (wave = one node-head). lane = (half = lane>>5 edge
// parity, ch2 = (lane&31)*2 channel pair). Per 8-edge iter: 8 uniform scalar
// idx loads + 8 uniform a_s loads + 4 gathers/lane (each 32-lane half reads
// a contiguous 128B slab of the 2.56MB head slice). Branchless tail (clamp
// idx, ex=0 past deg). Epilogue: shfl_xor(32) for den/acc; lanes<32 store.
// mode 0: out[n,c] = ELU(v + b[c]);  mode 1: out[n,c] = v.
__global__ __launch_bounds__(256) void gat_aggregate_kernel(
    const int* __restrict__ cnt, const int* __restrict__ ell,
    const __half* __restrict__ h16, const float* __restrict__ a_s,
    const float* __restrict__ a_d, const float* __restrict__ b,
    float* __restrict__ out, int N, int mode) {
  const int bid = blockIdx.x;
  const int hd = bid & 3;
  const int nn = __builtin_amdgcn_readfirstlane(
      (bid >> 2) * 4 + (threadIdx.x >> 6));
  if (nn >= N) return;
  const int lane = threadIdx.x & 63;
  const int half = lane >> 5;
  const int ch2 = (lane & 31) * 2;
  const float ad = a_d[nn * HEADS + hd];
  const int deg = __builtin_amdgcn_readfirstlane(cnt[nn * CNTS]);
  const int* __restrict__ rowp = ell + nn * ELLW;
  const unsigned nclamp = (unsigned)(N - 1);
  const char* __restrict__ hsl =
      (const char*)h16 + (size_t)hd * N * (CDIM * 2);  // head slice, bytes
  const unsigned choff = (unsigned)(ch2 * 2);          // byte offset in row
  float accL = 0.f, accH = 0.f, den = 0.f;

  for (int j0 = 0; j0 < deg; j0 += 8) {
    // uniform index batch (slots >= deg read garbage -> clamped, unused)
    unsigned su[8];
#pragma unroll
    for (int j = 0; j < 8; ++j) {
      const unsigned s = (unsigned)rowp[j0 + j];
      su[j] = (s > nclamp) ? nclamp : s;
    }
    // uniform scores + per-lane gathers (4 edges per half)
    float asv[8];
#pragma unroll
    for (int j = 0; j < 8; ++j) asv[j] = a_s[su[j] * HEADS + hd];
    unsigned hv[4];
#pragma unroll
    for (int k = 0; k < 4; ++k)
      hv[k] = *(const unsigned*)(hsl + ((size_t)su[2 * k + half] << 7) + choff);
    // compute pass: branchless (ex=0 past deg; 0 * finite = 0)
#pragma unroll
    for (int k = 0; k < 4; ++k) {
      const int j = 2 * k + half;
      float a = asv[j] + ad;
      a = fmaxf(a, 0.2f * a);
      const float ex = (j0 + j < deg) ? __expf(a) : 0.f;
      den += ex;
      fma_mix2(accL, accH, hv[k], ex);
    }
  }
  den += __shfl_xor(den, 32);
  accL += __shfl_xor(accL, 32);
  accH += __shfl_xor(accH, 32);
  if (half == 0) {
    const float inv = 1.f / den;
    float u0 = accL * inv, u1 = accH * inv;
    if (mode == 0) {
      const float2 bb = *(const float2*)(b + hd * CDIM + ch2);
      u0 += bb.x; u1 += bb.y;
      u0 = (u0 > 0.f) ? u0 : (__expf(u0) - 1.f);
      u1 = (u1 > 0.f) ? u1 : (__expf(u1) - 1.f);
    }
    *(float2*)(out + (size_t)nn * HC + hd * CDIM + ch2) = make_float2(u0, u1);
  }
}

// ---- fused output head: out[n,:] = (mean_h agg[n,h,:] + b2) @ Wout + bout --
// (verbatim r7) one wave per node; lane = channel c; shfl butterfly.
__global__ __launch_bounds__(256) void final_fused_kernel(
    const float* __restrict__ agg, const float* __restrict__ b2,
    const float* __restrict__ Wout, const float* __restrict__ bout,
    float* __restrict__ out, int N) {
  const int n = blockIdx.x * 4 + (threadIdx.x >> 6);
  const int c = threadIdx.x & 63;
  if (n >= N) return;
  const float* ar = agg + (size_t)n * HC;
  const float m = 0.25f * (ar[c] + ar[c + 64] + ar[c + 128] + ar[c + 192]) +
                  b2[c];
  const float4* wr = (const float4*)(Wout + c * 16);
  const float4 w0 = wr[0], w1 = wr[1], w2 = wr[2], w3 = wr[3];
  float p[16] = {m * w0.x, m * w0.y, m * w0.z, m * w0.w,
                 m * w1.x, m * w1.y, m * w1.z, m * w1.w,
                 m * w2.x, m * w2.y, m * w2.z, m * w2.w,
                 m * w3.x, m * w3.y, m * w3.z, m * w3.w};
#pragma unroll
  for (int off = 1; off < 64; off <<= 1)
#pragma unroll
    for (int j = 0; j < 16; ++j) p[j] += __shfl_xor(p[j], off);
  if (c == 0) {
    float* op = out + (size_t)n * 16;
    *(float4*)op = make_float4(p[0] + bout[0], p[1] + bout[1],
                               p[2] + bout[2], p[3] + bout[3]);
    *(float4*)(op + 4) = make_float4(p[4] + bout[4], p[5] + bout[5],
                                     p[6] + bout[6], p[7] + bout[7]);
    *(float4*)(op + 8) = make_float4(p[8] + bout[8], p[9] + bout[9],
                                     p[10] + bout[10], p[11] + bout[11]);
    *(float4*)(op + 12) = make_float4(p[12] + bout[12], p[13] + bout[13],
                                      p[14] + bout[14], p[15] + bout[15]);
  }
}

extern "C" void kernel_launch(void* const* d_in, const int* in_sizes, int n_in,
                              void* d_out, int out_size, void* d_ws, size_t ws_size,
                              hipStream_t stream) {
  const float* x      = (const float*)d_in[0];
  const int*   eidx   = (const int*)d_in[1];
  const float* W1     = (const float*)d_in[2];
  const float* att_s1 = (const float*)d_in[3];
  const float* att_d1 = (const float*)d_in[4];
  const float* b1     = (const float*)d_in[5];
  const float* W2     = (const float*)d_in[6];
  const float* att_s2 = (const float*)d_in[7];
  const float* att_d2 = (const float*)d_in[8];
  const float* b2     = (const float*)d_in[9];
  const float* Wout   = (const float*)d_in[10];
  const float* bout   = (const float*)d_in[11];
  float* out          = (float*)d_out;

  const int N     = in_sizes[0] / 128;   // 20000
  const int E_raw = in_sizes[1] / 2;     // 640000
  const int Etot  = E_raw + N;           // + self loops
  const int* src = eidx;
  const int* dst = eidx + E_raw;

  // ---- workspace layout ----
  float* ws = (float*)d_ws;
  float* buf_agg = ws;                          // [N,256] agg1/ELU out, agg2
  float* buf_as  = buf_agg + (size_t)N * HC;    // [N,4]
  float* buf_ad  = buf_as + (size_t)N * HEADS;  // [N,4]
  __half* h16    = (__half*)(buf_ad + (size_t)N * HEADS);  // [4][N][64] f16
  int* cnt  = (int*)(h16 + (size_t)N * HC);     // [N*CNTS] padded counters
  int* ell  = cnt + (size_t)N * CNTS;           // [N*ELLW]
  uintptr_t wp = ((uintptr_t)(ell + (size_t)N * ELLW) + 15) & ~(uintptr_t)15;
  short* wt1_hi = (short*)wp;                   // [256][128]
  short* wt1_lo = wt1_hi + 256 * 128;
  short* wt2_hi = wt1_lo + 256 * 128;           // [256][256]
  short* wt2_lo = wt2_hi + 256 * 256;

  const dim3 blk(256);
  const int chunk_sz = (Etot + NCHUNK - 1) / NCHUNK;
  const dim3 g_gemm((N + 63) / 64, 2);
  const dim3 blk_gemm(128);
  const int g_agg = ((N + 3) / 4) * 4;   // %8 == 0 at N=20000

  // ================= weight pack + cnt zero + ELL build =================
  pack_w12_kernel<<<(384 * 256 + 255) / 256, blk, 0, stream>>>(
      W1, wt1_hi, wt1_lo, W2, wt2_hi, wt2_lo, cnt, N);
  ell_scatter_kernel<<<NCHUNK * 8, blk, 0, stream>>>(src, dst, cnt, ell,
                                                     E_raw, Etot, chunk_sz);

  // ================= Layer 1 =================
  gemm_mfma_split<<<g_gemm, blk_gemm, 0, stream>>>(
      x, wt1_hi, wt1_lo, h16, att_s1, att_d1, buf_as, buf_ad, N, 128);
  gat_aggregate_kernel<<<g_agg, blk, 0, stream>>>(cnt, ell, h16, buf_as,
                                                  buf_ad, b1, buf_agg, N, 0);

  // ================= Layer 2 =================
  gemm_mfma_split<<<g_gemm, blk_gemm, 0, stream>>>(
      buf_agg, wt2_hi, wt2_lo, h16, att_s2, att_d2, buf_as, buf_ad, N, 256);
  gat_aggregate_kernel<<<g_agg, blk, 0, stream>>>(cnt, ell, h16, buf_as,
                                                  buf_ad, b2, buf_agg, N, 1);

  // ================= Output head (mean + bias + Wout fused) =================
  final_fused_kernel<<<(N + 3) / 4, blk, 0, stream>>>(buf_agg, b2, Wout, bout,
                                                      out, N);
}

// Round 8
// 255.334 us; speedup vs baseline: 1.4294x; 1.4294x over previous
//
#include <hip/hip_runtime.h>
#include <hip/hip_bf16.h>
#include <hip/hip_fp16.h>

// ---------------------------------------------------------------------------
// 2-layer GAT (PyG GATConv semantics).
// Round 19 = r17 base (257.3us) with:
//  (a) aggregate REVERTED to r14 wave-per-node all-heads form (r18's
//      head-partitioned variant was VALU-bound: 97% busy, 103us — dead branch);
//      h16 back to node-major [N][256];
//  (b) ONE new delta: GEMM blocks widened 128->256 thr (4 waves = 4 heads,
//      full 64x256 tile per block). A-tile LDS staging done in a single pass
//      (u = tid) and amortized over 4 consuming waves instead of 2; grid
//      313 1-D blocks. MFMA core + epilogue numerics byte-identical.
// Kept from r17: XCD-bucketed ell_scatter; padded per-line counters zeroed in
// pack_w12; fused mean+bias+Wout output head.
// ---------------------------------------------------------------------------

#define HEADS 4
#define CDIM 64
#define HC 256   // HEADS*CDIM
#define ELLW 96  // ELL row stride (ints)
#define CNTS 16  // cnt stride in ints (64B line per counter)
#define NCHUNK 320  // edge chunks; grid = NCHUNK*8 (nwg%8==0)

typedef __attribute__((ext_vector_type(8))) short bf16x8;   // 8 bf16 = 4 VGPR
typedef __attribute__((ext_vector_type(4))) float f32x4;    // MFMA acc

__device__ __forceinline__ short f32_to_bf16_rne(float v) {
  unsigned u = __float_as_uint(v);
  unsigned r = (u + 0x7FFFu + ((u >> 16) & 1u)) >> 16;
  return (short)r;
}
__device__ __forceinline__ float bf16_bits_to_f32(short s) {
  return __uint_as_float(((unsigned)(unsigned short)s) << 16);
}

// acc_lo += f16lo(reg)*ex ; acc_hi += f16hi(reg)*ex   (f32 accumulate)
__device__ __forceinline__ void fma_mix2(float& alo, float& ahi,
                                         unsigned reg, float ex) {
  asm("v_fma_mix_f32 %0, %2, %3, %0 op_sel:[0,0,0] op_sel_hi:[1,0,0]\n\t"
      "v_fma_mix_f32 %1, %2, %3, %1 op_sel:[1,0,0] op_sel_hi:[1,0,0]"
      : "+v"(alo), "+v"(ahi)
      : "v"(reg), "v"(ex));
}

// ------ weight pack (W1+W2 one launch) + cnt-line zeroing (fused) ----------
__global__ __launch_bounds__(256) void pack_w12_kernel(
    const float* __restrict__ W1, short* __restrict__ W1h,
    short* __restrict__ W1l, const float* __restrict__ W2,
    short* __restrict__ W2h, short* __restrict__ W2l,
    int* __restrict__ cnt, int N) {
  const int i = blockIdx.x * 256 + threadIdx.x;
  if (i < N) cnt[i * CNTS] = 0;   // one counter per 64B line
  if (i < 128 * 256) {
    const int k = i >> 8, n = i & 255;
    const float v = W1[i];
    const short hi = f32_to_bf16_rne(v);
    W1h[n * 128 + k] = hi;
    W1l[n * 128 + k] = f32_to_bf16_rne(v - bf16_bits_to_f32(hi));
  } else {
    const int j = i - 128 * 256;
    if (j >= 256 * 256) return;
    const int k = j >> 8, n = j & 255;
    const float v = W2[j];
    const short hi = f32_to_bf16_rne(v);
    W2h[n * 256 + k] = hi;
    W2l[n * 256 + k] = f32_to_bf16_rne(v - bf16_bits_to_f32(hi));
  }
}

// ---------------- split-bf16 MFMA GEMM: h = A[M,K] @ W[K,256] --------------
// r19: block = 256 thr (4 waves); wave w = head w, cols col0 = w*64.
// One block owns a full 64-row x 256-col tile. A staged f32->hi/lo bf16
// through LDS in a SINGLE pass (256 thr stage 64x32), amortized over 4
// consuming waves. B frags direct from global (L2-resident).
// Epilogue: f16 h write (node-major [M][256]) + fused a_s/a_d scores.
__global__ __launch_bounds__(256) void gemm_mfma_split(
    const float* __restrict__ A, const short* __restrict__ Wt_hi,
    const short* __restrict__ Wt_lo, __half* __restrict__ h16,
    const float* __restrict__ att_s, const float* __restrict__ att_d,
    float* __restrict__ a_s, float* __restrict__ a_d, int M, int K) {
  __shared__ alignas(16) short As_hi[64 * 32];
  __shared__ alignas(16) short As_lo[64 * 32];
  const int t = threadIdx.x;
  const int wave = t >> 6;         // == head
  const int lane = t & 63;
  const int quad = lane >> 4;
  const int m16 = lane & 15;
  const int row0 = blockIdx.x * 64;
  const int col0 = wave * 64;
  const int head = wave;

  f32x4 acc[4][4] = {};  // [mt][nt]

  for (int k0 = 0; k0 < K; k0 += 32) {
    if (k0) __syncthreads();
    {
      const int r = t >> 2, seg = t & 3;   // single-pass staging: 64x32
      const int gr = row0 + r;
      float vv[8] = {0.f, 0.f, 0.f, 0.f, 0.f, 0.f, 0.f, 0.f};
      if (gr < M) {
        const float* ap = A + (size_t)gr * K + k0 + seg * 8;
        const float4 v0 = *(const float4*)ap;
        const float4 v1 = *(const float4*)(ap + 4);
        vv[0] = v0.x; vv[1] = v0.y; vv[2] = v0.z; vv[3] = v0.w;
        vv[4] = v1.x; vv[5] = v1.y; vv[6] = v1.z; vv[7] = v1.w;
      }
      bf16x8 h8, l8;
#pragma unroll
      for (int j = 0; j < 8; ++j) {
        const short hi = f32_to_bf16_rne(vv[j]);
        h8[j] = hi;
        l8[j] = f32_to_bf16_rne(vv[j] - bf16_bits_to_f32(hi));
      }
      *(bf16x8*)(As_hi + r * 32 + seg * 8) = h8;
      *(bf16x8*)(As_lo + r * 32 + seg * 8) = l8;
    }
    bf16x8 b_hi[4], b_lo[4];
#pragma unroll
    for (int nt = 0; nt < 4; ++nt) {
      const size_t off = (size_t)(col0 + nt * 16 + m16) * K + k0 + quad * 8;
      b_hi[nt] = *(const bf16x8*)(Wt_hi + off);
      b_lo[nt] = *(const bf16x8*)(Wt_lo + off);
    }
    __syncthreads();
    bf16x8 a_hi[4], a_lo[4];
#pragma unroll
    for (int mt = 0; mt < 4; ++mt) {
      const int off = (mt * 16 + m16) * 32 + quad * 8;
      a_hi[mt] = *(const bf16x8*)(As_hi + off);
      a_lo[mt] = *(const bf16x8*)(As_lo + off);
    }
#pragma unroll
    for (int mt = 0; mt < 4; ++mt)
#pragma unroll
      for (int nt = 0; nt < 4; ++nt) {
        acc[mt][nt] = __builtin_amdgcn_mfma_f32_16x16x32_bf16(
            a_hi[mt], b_hi[nt], acc[mt][nt], 0, 0, 0);
        acc[mt][nt] = __builtin_amdgcn_mfma_f32_16x16x32_bf16(
            a_hi[mt], b_lo[nt], acc[mt][nt], 0, 0, 0);
        acc[mt][nt] = __builtin_amdgcn_mfma_f32_16x16x32_bf16(
            a_lo[mt], b_hi[nt], acc[mt][nt], 0, 0, 0);
      }
  }
  float sa[4], da[4];
#pragma unroll
  for (int nt = 0; nt < 4; ++nt) {
    sa[nt] = att_s[col0 + nt * 16 + m16];
    da[nt] = att_d[col0 + nt * 16 + m16];
  }
#pragma unroll
  for (int mt = 0; mt < 4; ++mt)
#pragma unroll
    for (int r = 0; r < 4; ++r) {
      const int gr = row0 + mt * 16 + quad * 4 + r;
      float ps = acc[mt][0][r] * sa[0] + acc[mt][1][r] * sa[1] +
                 acc[mt][2][r] * sa[2] + acc[mt][3][r] * sa[3];
      float pd = acc[mt][0][r] * da[0] + acc[mt][1][r] * da[1] +
                 acc[mt][2][r] * da[2] + acc[mt][3][r] * da[3];
#pragma unroll
      for (int off = 1; off <= 8; off <<= 1) {
        ps += __shfl_xor(ps, off);
        pd += __shfl_xor(pd, off);
      }
      if (gr < M) {
        if (m16 == 0) {
          a_s[gr * HEADS + head] = ps;
          a_d[gr * HEADS + head] = pd;
        }
#pragma unroll
        for (int nt = 0; nt < 4; ++nt)
          h16[(size_t)gr * HC + col0 + nt * 16 + m16] =
              __float2half(acc[mt][nt][r]);
      }
    }
}

// ============ ELL build: XCD-bucketed scatter (write-combining) ============
// grid = NCHUNK*8. block (chunk = bx>>3, g = bx&7) scans its chunk's edges
// and keeps those with dst-bucket group ((d>>8)&7) == g.
__global__ __launch_bounds__(256) void ell_scatter_kernel(
    const int* __restrict__ src, const int* __restrict__ dst,
    int* __restrict__ cnt, int* __restrict__ ell, int E_raw, int Etot,
    int chunk_sz) {
  const int g = blockIdx.x & 7;
  const int e0 = (blockIdx.x >> 3) * chunk_sz;
  int e1 = e0 + chunk_sz;
  if (e1 > Etot) e1 = Etot;
  for (int e = e0 + threadIdx.x; e < e1; e += 256) {
    const int d = (e < E_raw) ? dst[e] : (e - E_raw);
    if (((d >> 8) & 7) != g) continue;
    const int s = (e < E_raw) ? src[e] : (e - E_raw);
    const int pos = atomicAdd(&cnt[d * CNTS], 1);
    if (pos < ELLW) ell[d * ELLW + pos] = s;  // P(overflow) ~ 7e-18
  }
}

// ================= fused softmax + aggregation (f16 gather) ================
// (r14 proven form) grid = ceil(N/4) blocks x 256 thr; wave = one node (ALL
// heads). lane covers channels lane*4..+3 (head hd = lane>>4). Per edge one
// uint2 gather/lane = contiguous 512B h16 row across the wave. ELL indices
// wave-uniform scalar loads; branchless tail (ex=0 past deg, clamped idx).
// mode 0: out[n,c] = ELU(v + b[c]);  mode 1: out[n,c] = v.
__global__ __launch_bounds__(256) void gat_aggregate_kernel(
    const int* __restrict__ cnt, const int* __restrict__ ell,
    const __half* __restrict__ h16, const float* __restrict__ a_s,
    const float* __restrict__ a_d, const float* __restrict__ b,
    float* __restrict__ out, int N, int mode) {
  const int nn = __builtin_amdgcn_readfirstlane(
      blockIdx.x * 4 + (threadIdx.x >> 6));
  if (nn >= N) return;
  const int lane = threadIdx.x & 63;
  const int hd = lane >> 4;
  const float ad = a_d[nn * HEADS + hd];
  const int deg = __builtin_amdgcn_readfirstlane(cnt[nn * CNTS]);
  const int* __restrict__ rowp = ell + nn * ELLW;
  const unsigned nclamp = (unsigned)(N - 1);
  const char* __restrict__ hby = (const char*)h16;
  const unsigned lo8 = (unsigned)lane * 8u;   // loop-invariant voffset
  float acc0 = 0.f, acc1 = 0.f, acc2 = 0.f, acc3 = 0.f, den = 0.f;

  for (int j0 = 0; j0 < deg; j0 += 8) {
    // uniform index batch (slots >= deg read garbage -> clamped, unused)
    unsigned su[8];
#pragma unroll
    for (int j = 0; j < 8; ++j) {
      const unsigned s = (unsigned)rowp[j0 + j];
      su[j] = (s > nclamp) ? nclamp : s;
    }
    // gather pass: 16 loads in flight (8 a_s + 8 h16)
    float asv[8];
    uint2 hv[8];
#pragma unroll
    for (int j = 0; j < 8; ++j) {
      asv[j] = a_s[su[j] * HEADS + hd];
      hv[j] = *(const uint2*)(hby + (((size_t)su[j]) << 9) + lo8);
    }
    // compute pass: branchless (ex=0 past deg; 0 * finite = 0)
#pragma unroll
    for (int j = 0; j < 8; ++j) {
      float a = asv[j] + ad;
      a = fmaxf(a, 0.2f * a);
      const float ex = (j0 + j < deg) ? __expf(a) : 0.f;
      den += ex;
      fma_mix2(acc0, acc1, hv[j].x, ex);
      fma_mix2(acc2, acc3, hv[j].y, ex);
    }
  }

  const float inv = 1.f / den;
  float u0 = acc0 * inv, u1 = acc1 * inv, u2 = acc2 * inv, u3 = acc3 * inv;
  if (mode == 0) {
    const float4 bb = *(const float4*)(b + lane * 4);
    u0 += bb.x; u1 += bb.y; u2 += bb.z; u3 += bb.w;
    u0 = (u0 > 0.f) ? u0 : (__expf(u0) - 1.f);
    u1 = (u1 > 0.f) ? u1 : (__expf(u1) - 1.f);
    u2 = (u2 > 0.f) ? u2 : (__expf(u2) - 1.f);
    u3 = (u3 > 0.f) ? u3 : (__expf(u3) - 1.f);
  }
  *(float4*)(out + (size_t)nn * HC + lane * 4) = make_float4(u0, u1, u2, u3);
}

// ---- fused output head: out[n,:] = (mean_h agg[n,h,:] + b2) @ Wout + bout --
// one wave per node; lane = channel c; shfl butterfly.
__global__ __launch_bounds__(256) void final_fused_kernel(
    const float* __restrict__ agg, const float* __restrict__ b2,
    const float* __restrict__ Wout, const float* __restrict__ bout,
    float* __restrict__ out, int N) {
  const int n = blockIdx.x * 4 + (threadIdx.x >> 6);
  const int c = threadIdx.x & 63;
  if (n >= N) return;
  const float* ar = agg + (size_t)n * HC;
  const float m = 0.25f * (ar[c] + ar[c + 64] + ar[c + 128] + ar[c + 192]) +
                  b2[c];
  const float4* wr = (const float4*)(Wout + c * 16);
  const float4 w0 = wr[0], w1 = wr[1], w2 = wr[2], w3 = wr[3];
  float p[16] = {m * w0.x, m * w0.y, m * w0.z, m * w0.w,
                 m * w1.x, m * w1.y, m * w1.z, m * w1.w,
                 m * w2.x, m * w2.y, m * w2.z, m * w2.w,
                 m * w3.x, m * w3.y, m * w3.z, m * w3.w};
#pragma unroll
  for (int off = 1; off < 64; off <<= 1)
#pragma unroll
    for (int j = 0; j < 16; ++j) p[j] += __shfl_xor(p[j], off);
  if (c == 0) {
    float* op = out + (size_t)n * 16;
    *(float4*)op = make_float4(p[0] + bout[0], p[1] + bout[1],
                               p[2] + bout[2], p[3] + bout[3]);
    *(float4*)(op + 4) = make_float4(p[4] + bout[4], p[5] + bout[5],
                                     p[6] + bout[6], p[7] + bout[7]);
    *(float4*)(op + 8) = make_float4(p[8] + bout[8], p[9] + bout[9],
                                     p[10] + bout[10], p[11] + bout[11]);
    *(float4*)(op + 12) = make_float4(p[12] + bout[12], p[13] + bout[13],
                                      p[14] + bout[14], p[15] + bout[15]);
  }
}

extern "C" void kernel_launch(void* const* d_in, const int* in_sizes, int n_in,
                              void* d_out, int out_size, void* d_ws, size_t ws_size,
                              hipStream_t stream) {
  const float* x      = (const float*)d_in[0];
  const int*   eidx   = (const int*)d_in[1];
  const float* W1     = (const float*)d_in[2];
  const float* att_s1 = (const float*)d_in[3];
  const float* att_d1 = (const float*)d_in[4];
  const float* b1     = (const float*)d_in[5];
  const float* W2     = (const float*)d_in[6];
  const float* att_s2 = (const float*)d_in[7];
  const float* att_d2 = (const float*)d_in[8];
  const float* b2     = (const float*)d_in[9];
  const float* Wout   = (const float*)d_in[10];
  const float* bout   = (const float*)d_in[11];
  float* out          = (float*)d_out;

  const int N     = in_sizes[0] / 128;   // 20000
  const int E_raw = in_sizes[1] / 2;     // 640000
  const int Etot  = E_raw + N;           // + self loops
  const int* src = eidx;
  const int* dst = eidx + E_raw;

  // ---- workspace layout ----
  float* ws = (float*)d_ws;
  float* buf_agg = ws;                          // [N,256] agg1/ELU out, agg2
  float* buf_as  = buf_agg + (size_t)N * HC;    // [N,4]
  float* buf_ad  = buf_as + (size_t)N * HEADS;  // [N,4]
  __half* h16    = (__half*)(buf_ad + (size_t)N * HEADS);  // [N,256] f16
  int* cnt  = (int*)(h16 + (size_t)N * HC);     // [N*CNTS] padded counters
  int* ell  = cnt + (size_t)N * CNTS;           // [N*ELLW]
  uintptr_t wp = ((uintptr_t)(ell + (size_t)N * ELLW) + 15) & ~(uintptr_t)15;
  short* wt1_hi = (short*)wp;                   // [256][128]
  short* wt1_lo = wt1_hi + 256 * 128;
  short* wt2_hi = wt1_lo + 256 * 128;           // [256][256]
  short* wt2_lo = wt2_hi + 256 * 256;

  const dim3 blk(256);
  const int chunk_sz = (Etot + NCHUNK - 1) / NCHUNK;
  const int g_gemm = (N + 63) / 64;   // 313 blocks, 256 thr (4 waves = heads)
  const int g_agg = (N + 3) / 4;

  // ================= weight pack + cnt zero + ELL build =================
  pack_w12_kernel<<<(384 * 256 + 255) / 256, blk, 0, stream>>>(
      W1, wt1_hi, wt1_lo, W2, wt2_hi, wt2_lo, cnt, N);
  ell_scatter_kernel<<<NCHUNK * 8, blk, 0, stream>>>(src, dst, cnt, ell,
                                                     E_raw, Etot, chunk_sz);

  // ================= Layer 1 =================
  gemm_mfma_split<<<g_gemm, blk, 0, stream>>>(
      x, wt1_hi, wt1_lo, h16, att_s1, att_d1, buf_as, buf_ad, N, 128);
  gat_aggregate_kernel<<<g_agg, blk, 0, stream>>>(cnt, ell, h16, buf_as,
                                                  buf_ad, b1, buf_agg, N, 0);

  // ================= Layer 2 =================
  gemm_mfma_split<<<g_gemm, blk, 0, stream>>>(
      buf_agg, wt2_hi, wt2_lo, h16, att_s2, att_d2, buf_as, buf_ad, N, 256);
  gat_aggregate_kernel<<<g_agg, blk, 0, stream>>>(cnt, ell, h16, buf_as,
                                                  buf_ad, b2, buf_agg, N, 1);

  // ================= Output head (mean + bias + Wout fused) =================
  final_fused_kernel<<<(N + 3) / 4, blk, 0, stream>>>(buf_agg, b2, Wout, bout,
                                                      out, N);
}